// Round 1
// 203.479 us; speedup vs baseline: 1.0061x; 1.0061x over previous
//
#include <hip/hip_runtime.h>
#include <hip/hip_bf16.h>
#include <math.h>

#define N_NODES 4096
#define FDIM 512            // K of both GEMMs (F_in = H*D = 512)
#define D 64
#define H 8
#define NWORDS (N_NODES / 64)

typedef __attribute__((ext_vector_type(8))) short bf16x8;   // 8 bf16 = 4 VGPRs
typedef __attribute__((ext_vector_type(4))) float f32x4;

__device__ inline short f2bf(float x) {                     // RNE
    return (short)((__builtin_bit_cast(unsigned int, x) + 0x8000u) >> 16);
}
__device__ inline float b2f(unsigned short s) {
    return __builtin_bit_cast(float, (unsigned int)s << 16);
}

__device__ inline int sext_bit(unsigned int v, int j) {     // all-ones iff bit j set
#if defined(__has_builtin) && __has_builtin(__builtin_amdgcn_sbfe)
    return __builtin_amdgcn_sbfe((int)v, j, 1);
#else
    return ((int)(v << (31 - j))) >> 31;
#endif
}

// monotonic float<->uint encoding so unsigned atomicMax == float max
__device__ inline unsigned fenc(float f) {
    unsigned u = __builtin_bit_cast(unsigned, f);
    return (u & 0x80000000u) ? ~u : (u | 0x80000000u);
}
__device__ inline float fdec(unsigned e) {
    unsigned u = (e & 0x80000000u) ? (e & 0x7FFFFFFFu) : ~e;
    return __builtin_bit_cast(float, u);
}

// async global->LDS 16B copy (DMA). LDS dst must be wave-uniform base + lane*16.
__device__ inline void gl2lds16(const void* g, void* l) {
#if defined(__has_builtin) && __has_builtin(__builtin_amdgcn_global_load_lds)
    __builtin_amdgcn_global_load_lds(
        (const __attribute__((address_space(1))) unsigned int*)g,
        (__attribute__((address_space(3))) unsigned int*)l, 16, 0, 0);
#else
    *(uint4*)l = *(const uint4*)g;
#endif
}

// ---------------------------------------------------------------- fused preprocessing
// band 0: zero cm/gmax; bands: adj->bits (8/thread, int4 loads) | X->bf16 (4/thread) | W | W_o
#define NB_BITS (N_NODES * N_NODES / 2048)     // 8 adj per thread
#define NB_X    (N_NODES * FDIM / 1024)        // 4 floats per thread
#define NB_W    (H * FDIM * D / 256)
#define NB_WO   (FDIM * D / 256)
__global__ void k_pre(const int* __restrict__ adj, const float* __restrict__ x,
                      const float* __restrict__ W, const float* __restrict__ Wo,
                      unsigned int* __restrict__ bits32, short* __restrict__ Xbf,
                      short* __restrict__ WF, short* __restrict__ WoF,
                      float* __restrict__ cm1, float* __restrict__ cm2,
                      unsigned* __restrict__ gmaxe1, unsigned* __restrict__ gmaxe2) {
    const int b = blockIdx.x, t = threadIdx.x;
    if (b == 0) {
        for (int i = t; i < H * D; i += 256) cm1[i] = 0.f;
        if (t < D) cm2[t] = 0.f;
        if (t < H) gmaxe1[t] = 0u;
        if (t == 0) gmaxe2[0] = 0u;
        return;
    }
    if (b < 1 + NB_BITS) {
        const int tid  = (b - 1) * 256 + t;     // one byte (8 adj) per thread
        const size_t e0 = (size_t)tid * 8;
        int4 a0 = *(const int4*)&adj[e0];
        int4 a1 = *(const int4*)&adj[e0 + 4];
        unsigned by = (unsigned)(a0.x != 0)       | ((unsigned)(a0.y != 0) << 1)
                    | ((unsigned)(a0.z != 0) << 2) | ((unsigned)(a0.w != 0) << 3)
                    | ((unsigned)(a1.x != 0) << 4) | ((unsigned)(a1.y != 0) << 5)
                    | ((unsigned)(a1.z != 0) << 6) | ((unsigned)(a1.w != 0) << 7);
        unsigned v = by | (__shfl_xor((int)by, 1) << 8);
        v = v | ((unsigned)__shfl_xor((int)v, 2) << 16);
        if ((t & 3) == 0) bits32[tid >> 2] = v;
        return;
    }
    if (b < 1 + NB_BITS + NB_X) {
        const size_t i4 = ((size_t)(b - 1 - NB_BITS) * 256 + t) * 4;
        float4 v = *(const float4*)&x[i4];
        ushort4 o;
        o.x = (unsigned short)f2bf(v.x); o.y = (unsigned short)f2bf(v.y);
        o.z = (unsigned short)f2bf(v.z); o.w = (unsigned short)f2bf(v.w);
        *(ushort4*)&Xbf[i4] = o;
        return;
    }
    if (b < 1 + NB_BITS + NB_X + NB_W) {
        const size_t idx = (size_t)(b - 1 - NB_BITS - NB_X) * 256 + t;   // (h*512+k)*64+d
        const int d = idx & 63;
        const int k = (int)(idx >> 6) & 511;
        const int h = (int)(idx >> 15);
        WF[(((size_t)h * 64 + (k >> 3)) * 64 + d) * 8 + (k & 7)] = f2bf(W[idx]);
        return;
    }
    {
        const size_t idx = (size_t)(b - 1 - NB_BITS - NB_X - NB_W) * 256 + t;  // k*64+d
        const int d = idx & 63;
        const int k = (int)(idx >> 6);
        WoF[(((size_t)(k >> 3)) * 64 + d) * 8 + (k & 7)] = f2bf(Wo[idx]);
    }
}

// ---------------------------------------------------------------- MFMA GEMM [N,512]@[512,64] per head
// bf16 A from global; writes bf16 frag copy of C, fused fs/fd row dot-products,
// and fused per-head stats: gmax(fd) via encoded atomicMax, colmean via atomicAdd.
__global__ void __launch_bounds__(256) k_gemm(
    const short* __restrict__ Xbf, const short* __restrict__ WF,
    const float* __restrict__ av, const float* __restrict__ bv,
    short* __restrict__ WBout, float* __restrict__ fs, float* __restrict__ fd,
    unsigned* __restrict__ gmaxe, float* __restrict__ cm) {
    const int h  = blockIdx.y;
    const int i0 = blockIdx.x * 64;
    const int t = threadIdx.x, w = t >> 6, lane = t & 63;
    const int li = lane & 15, quad = lane >> 4, k0 = quad * 8;
    const int row_a = i0 + w * 16 + li;
    const short* __restrict__ Xr  = Xbf + (size_t)row_a * FDIM;
    const short* __restrict__ WFh = WF + (size_t)h * 64 * D * 8;

    f32x4 c0 = {0.f, 0.f, 0.f, 0.f}, c1 = c0, c2 = c0, c3 = c0;
    #pragma unroll 4
    for (int kt = 0; kt < FDIM; kt += 32) {
        bf16x8 a = *(const bf16x8*)&Xr[kt + k0];
        const short* bb = WFh + (size_t)((kt >> 3) + quad) * (D * 8) + li * 8;
        bf16x8 b0 = *(const bf16x8*)(bb);
        bf16x8 b1 = *(const bf16x8*)(bb + 128);
        bf16x8 b2 = *(const bf16x8*)(bb + 256);
        bf16x8 b3 = *(const bf16x8*)(bb + 384);
        c0 = __builtin_amdgcn_mfma_f32_16x16x32_bf16(a, b0, c0, 0, 0, 0);
        c1 = __builtin_amdgcn_mfma_f32_16x16x32_bf16(a, b1, c1, 0, 0, 0);
        c2 = __builtin_amdgcn_mfma_f32_16x16x32_bf16(a, b2, c2, 0, 0, 0);
        c3 = __builtin_amdgcn_mfma_f32_16x16x32_bf16(a, b3, c3, 0, 0, 0);
    }
    float av4[4], bv4[4];
    #pragma unroll
    for (int t4 = 0; t4 < 4; ++t4) {
        av4[t4] = av[h * D + t4 * 16 + li];
        bv4[t4] = bv[h * D + t4 * 16 + li];
    }
    float tiles[4][4];
    #pragma unroll
    for (int r = 0; r < 4; ++r) { tiles[0][r] = c0[r]; tiles[1][r] = c1[r]; tiles[2][r] = c2[r]; tiles[3][r] = c3[r]; }

    __shared__ float csum[4][64];
    __shared__ float red[4];
    float fdmax = -INFINITY;
    float s4[4] = {0.f, 0.f, 0.f, 0.f};

    #pragma unroll
    for (int r = 0; r < 4; ++r) {
        const int row = i0 + w * 16 + quad * 4 + r;
        float pa = 0.f, pb = 0.f;
        #pragma unroll
        for (int t4 = 0; t4 < 4; ++t4) {
            const float v = tiles[t4][r];
            const int d = t4 * 16 + li;
            WBout[((size_t)h * (N_NODES / 8) + (row >> 3)) * (D * 8) + d * 8 + (row & 7)] = f2bf(v);
            pa += v * av4[t4];
            pb += v * bv4[t4];
            s4[t4] += v;
        }
        #pragma unroll
        for (int off = 1; off < 16; off <<= 1) {
            pa += __shfl_xor(pa, off);
            pb += __shfl_xor(pb, off);
        }
        if (li == 0) {
            fs[(size_t)h * N_NODES + row] = pa;
            fd[(size_t)h * N_NODES + row] = pb;
        }
        fdmax = fmaxf(fdmax, pb);
    }
    fdmax = fmaxf(fdmax, __shfl_xor(fdmax, 16));
    fdmax = fmaxf(fdmax, __shfl_xor(fdmax, 32));
    if (lane == 0) red[w] = fdmax;
    #pragma unroll
    for (int t4 = 0; t4 < 4; ++t4) {
        s4[t4] += __shfl_xor(s4[t4], 16);
        s4[t4] += __shfl_xor(s4[t4], 32);
    }
    if (quad == 0)
        #pragma unroll
        for (int t4 = 0; t4 < 4; ++t4) csum[w][t4 * 16 + li] = s4[t4];
    __syncthreads();
    if (t == 0)
        atomicMax(gmaxe + h, fenc(fmaxf(fmaxf(red[0], red[1]), fmaxf(red[2], red[3]))));
    if (t < 64)
        atomicAdd(&cm[h * D + t],
                  (csum[0][t] + csum[1][t] + csum[2][t] + csum[3][t]) * (1.f / (float)N_NODES));
}

// ---------------------------------------------------------------- MFMA attention aggregation (j-split)
// 256 i-rows/block, 64 rows/wave. B-tile (16 KB) DMA'd to LDS, double-buffered
// with a COUNTED-vmcnt pipeline (T4): per tile {b1; load bits(t); stage(t+1);
// s_waitcnt vmcnt(4); b2; compute(t)} so the next tile's DMA stays in flight
// across the barrier (no full drain except the last tile).
// E/G exp tables hoisted to a one-shot prologue (whole slab, 4 KB LDS) — makes
// per-wave VMEM counts uniform (required for counted waits) and removes the
// old per-tile w0-divergent EG staging.
// Register budget: acc+c5 = 80 AGPR; bwa copy removed (bits single-buffered,
// bw[f].x/y/z/w read directly, s compile-time) so arch VGPR <= ~88 and
// __launch_bounds__(256,3) gets 3 waves/SIMD (was 2: 92+80=172 > 512/3).
__global__ void __launch_bounds__(256, 3) k_accum(
    const unsigned int* __restrict__ bits32,
    const short* __restrict__ WB,
    const float* __restrict__ fsb, const float* __restrict__ fdb,
    const unsigned* __restrict__ gmaxe,
    short* __restrict__ num, float* __restrict__ den, int kslab) {

    __shared__ __align__(16) short Bt[2][16 * 64 * 8];   // 2 x 16 KB
    __shared__ __align__(16) float Esh[512];             // exp(fd - gm), whole slab
    __shared__ __align__(16) float Gsh[512];             // exp(0.2*(fd - gm))

    const int h = blockIdx.y, i0 = blockIdx.x * 256, slab = blockIdx.z;
    const int t = threadIdx.x, w = t >> 6, lane = t & 63;
    const int li = lane & 15, quad = lane >> 4, k0 = quad * 8;
    const size_t ho = (size_t)h * N_NODES;
    const float  gm = fdec(gmaxe[h]);
    const float* __restrict__ fd = fdb + ho;
    const short* __restrict__ Bh = WB + (size_t)h * (N_NODES / 8) * D * 8;

    const int k_beg = slab * kslab;
    const int ntile = kslab / 128;

    auto stage = [&](int buf, int jtile) {
        const short* src = Bh + (size_t)(jtile >> 3) * (D * 8);
        #pragma unroll
        for (int p = 0; p < 4; ++p)
            gl2lds16(src + (size_t)(p * 256 + t) * 8, &Bt[buf][(p * 256 + t) * 8]);
    };

    // ---- prologue: tile-0 bits, stage tile 0, EG table, Rv, acc init
    int bito[4];
    #pragma unroll
    for (int f = 0; f < 4; ++f)
        bito[f] = (i0 + w * 64 + f * 16 + li) * (NWORDS * 2);
    uint4 bw[4];
    #pragma unroll
    for (int f = 0; f < 4; ++f)
        bw[f] = *(const uint4*)&bits32[(size_t)bito[f] + (k_beg >> 5)];
    stage(0, k_beg);
    {
        const int jj = t * 2;                 // whole-slab EG table, one shot
        if (jj < kslab) {
            float2 f2 = *(const float2*)&fd[k_beg + jj];
            Esh[jj]     = __expf(f2.x - gm);
            Esh[jj + 1] = __expf(f2.y - gm);
            Gsh[jj]     = __expf(0.2f * (f2.x - gm));
            Gsh[jj + 1] = __expf(0.2f * (f2.y - gm));
        }
    }
    float Rv[4];
    #pragma unroll
    for (int f = 0; f < 4; ++f)
        Rv[f] = __expf(-0.8f * (fsb[ho + i0 + w * 64 + f * 16 + li] + gm));

    f32x4 acc[4][4], c5[4];
    #pragma unroll
    for (int f = 0; f < 4; ++f) {
        #pragma unroll
        for (int q = 0; q < 4; ++q) acc[f][q] = (f32x4){0.f, 0.f, 0.f, 0.f};
        c5[f] = (f32x4){0.f, 0.f, 0.f, 0.f};
    }
    bf16x8 ones;
    #pragma unroll
    for (int j = 0; j < 8; ++j) ones[j] = (short)0x3F80;

    __syncthreads();   // drains prologue vmcnt (stage0, bits0) + EG lds writes

    for (int tile = 0; tile < ntile; ++tile) {
        const int jt = k_beg + tile * 128;
        // b1: all waves finished compute(tile-1) -> buf[(tile+1)&1] is free
        __builtin_amdgcn_s_barrier();
        if (tile > 0) {
            #pragma unroll
            for (int f = 0; f < 4; ++f)
                bw[f] = *(const uint4*)&bits32[(size_t)bito[f] + (jt >> 5)];
        }
        if (tile + 1 < ntile) {
            stage((tile + 1) & 1, jt + 128);
            // outstanding: stage(t)[4] + bits(t)[4] + stage(t+1)[4] -> keep 4 newest
            asm volatile("s_waitcnt vmcnt(4)" ::: "memory");
        } else {
            asm volatile("s_waitcnt vmcnt(0)" ::: "memory");
        }
        // b2: every wave drained its stage(tile) -> buf[tile&1] fully written
        __builtin_amdgcn_s_barrier();

        const short* Bl = Bt[tile & 1];
        const float* Ee = Esh + tile * 128;
        const float* Gg = Gsh + tile * 128;
        #pragma unroll
        for (int s = 0; s < 4; ++s) {
            const float4 e0 = *(const float4*)&Ee[s * 32 + k0];
            const float4 e1 = *(const float4*)&Ee[s * 32 + k0 + 4];
            const float4 g0 = *(const float4*)&Gg[s * 32 + k0];
            const float4 g1 = *(const float4*)&Gg[s * 32 + k0 + 4];
            float ev[8], gv[8];
            ev[0] = e0.x; ev[1] = e0.y; ev[2] = e0.z; ev[3] = e0.w;
            ev[4] = e1.x; ev[5] = e1.y; ev[6] = e1.z; ev[7] = e1.w;
            gv[0] = g0.x; gv[1] = g0.y; gv[2] = g0.z; gv[3] = g0.w;
            gv[4] = g1.x; gv[5] = g1.y; gv[6] = g1.z; gv[7] = g1.w;
            const short* bb = Bl + (size_t)((s * 4 + quad) * 64 + li) * 8;
            bf16x8 b0 = *(const bf16x8*)(bb);
            bf16x8 b1 = *(const bf16x8*)(bb + 128);
            bf16x8 b2 = *(const bf16x8*)(bb + 256);
            bf16x8 b3 = *(const bf16x8*)(bb + 384);
            #pragma unroll
            for (int f = 0; f < 4; ++f) {
                const unsigned int wsel = (s == 0) ? bw[f].x : (s == 1) ? bw[f].y
                                        : (s == 2) ? bw[f].z : bw[f].w;
                const unsigned int byt = (wsel >> k0) & 0xFFu;
                unsigned int pa[8];
                #pragma unroll
                for (int j = 0; j < 8; ++j) {
                    const float p = fmaxf(ev[j], gv[j] * Rv[f]);   // == leaky branch select
                    pa[j] = __builtin_bit_cast(unsigned int, p)
                            & (unsigned int)sext_bit(byt, j);
                }
                bf16x8 a;
                unsigned int* au = (unsigned int*)&a;
                au[0] = __builtin_amdgcn_perm(pa[1], pa[0], 0x07060302);
                au[1] = __builtin_amdgcn_perm(pa[3], pa[2], 0x07060302);
                au[2] = __builtin_amdgcn_perm(pa[5], pa[4], 0x07060302);
                au[3] = __builtin_amdgcn_perm(pa[7], pa[6], 0x07060302);
                __builtin_amdgcn_s_setprio(1);
                acc[f][0] = __builtin_amdgcn_mfma_f32_16x16x32_bf16(a, b0, acc[f][0], 0, 0, 0);
                acc[f][1] = __builtin_amdgcn_mfma_f32_16x16x32_bf16(a, b1, acc[f][1], 0, 0, 0);
                acc[f][2] = __builtin_amdgcn_mfma_f32_16x16x32_bf16(a, b2, acc[f][2], 0, 0, 0);
                acc[f][3] = __builtin_amdgcn_mfma_f32_16x16x32_bf16(a, b3, acc[f][3], 0, 0, 0);
                c5[f]     = __builtin_amdgcn_mfma_f32_16x16x32_bf16(a, ones, c5[f], 0, 0, 0);
                __builtin_amdgcn_s_setprio(0);
            }
        }
    }

    const size_t so = (size_t)(slab * gridDim.y + h);
    #pragma unroll
    for (int f = 0; f < 4; ++f) {
        #pragma unroll
        for (int t4 = 0; t4 < 4; ++t4)
            #pragma unroll
            for (int r = 0; r < 4; ++r) {
                const int row = i0 + w * 64 + f * 16 + quad * 4 + r;
                num[(so * N_NODES + row) * D + t4 * 16 + li] = f2bf(acc[f][t4][r]);
            }
        if (li == 0)
            #pragma unroll
            for (int r = 0; r < 4; ++r)
                den[so * N_NODES + i0 + w * 64 + f * 16 + quad * 4 + r] = c5[f][r];
    }
}

// ---------------------------------------------------------------- layer-1 combine (JS=8): norm+fallback+ELU, bf16 out
__global__ void k_post1(const short* __restrict__ num, const float* __restrict__ den,
                        const float* __restrict__ colmean, short* __restrict__ hcat) {
    const int h   = blockIdx.y;
    const int i0  = blockIdx.x * 64;
    const int t   = threadIdx.x;
    const int row = i0 + (t >> 2);
    const int cb  = (t & 3) * 16;
    const size_t HN = (size_t)gridDim.y * N_NODES;
    const size_t r0 = (size_t)h * N_NODES + row;
    float dsum = 0.f;
    #pragma unroll
    for (int s = 0; s < 8; ++s) dsum += den[s * HN + r0];
    const bool  uni  = !(dsum > 0.f);
    const float linv = uni ? 0.f : 1.f / dsum;
    #pragma unroll
    for (int c = 0; c < 4; ++c) {
        const int col = cb + c * 4;
        float4 v = {0.f, 0.f, 0.f, 0.f};
        #pragma unroll
        for (int s = 0; s < 8; ++s) {
            ushort4 a = *(const ushort4*)&num[(s * HN + r0) * D + col];
            v.x += b2f(a.x); v.y += b2f(a.y); v.z += b2f(a.z); v.w += b2f(a.w);
        }
        v.x *= linv; v.y *= linv; v.z *= linv; v.w *= linv;
        if (uni) v = *(const float4*)&colmean[h * D + col];
        v.x = v.x > 0.f ? v.x : __expf(v.x) - 1.f;
        v.y = v.y > 0.f ? v.y : __expf(v.y) - 1.f;
        v.z = v.z > 0.f ? v.z : __expf(v.z) - 1.f;
        v.w = v.w > 0.f ? v.w : __expf(v.w) - 1.f;
        ushort4 o;
        o.x = (unsigned short)f2bf(v.x); o.y = (unsigned short)f2bf(v.y);
        o.z = (unsigned short)f2bf(v.z); o.w = (unsigned short)f2bf(v.w);
        *(ushort4*)&hcat[(size_t)row * (H * D) + h * D + col] = o;
    }
}

// ---------------------------------------------------------------- layer-2 combine (JS=32) + ELU + log_softmax
__global__ void k_lsm(const short* __restrict__ num, const float* __restrict__ den,
                      const float* __restrict__ cm, float* __restrict__ out) {
    const int n    = blockIdx.x * 4 + (threadIdx.x >> 6);
    const int lane = threadIdx.x & 63;
    float v = 0.f, ds = 0.f;
    #pragma unroll
    for (int s = 0; s < 32; ++s)
        v += b2f((unsigned short)num[((size_t)s * N_NODES + n) * D + lane]);
    #pragma unroll
    for (int s = 0; s < 32; ++s) ds += den[(size_t)s * N_NODES + n];
    v = (ds > 0.f) ? v / ds : cm[lane];
    v = v > 0.f ? v : __expf(v) - 1.f;
    float mx = v;
    #pragma unroll
    for (int off = 32; off > 0; off >>= 1) mx = fmaxf(mx, __shfl_xor(mx, off));
    float ex = __expf(v - mx);
    float sum = ex;
    #pragma unroll
    for (int off = 32; off > 0; off >>= 1) sum += __shfl_xor(sum, off);
    out[(size_t)n * D + lane] = (v - mx) - __logf(sum);
}

// ----------------------------------------------------------------
extern "C" void kernel_launch(void* const* d_in, const int* in_sizes, int n_in,
                              void* d_out, int out_size, void* d_ws, size_t ws_size,
                              hipStream_t stream) {
    const float* x      = (const float*)d_in[0];
    const int*   adj    = (const int*)d_in[1];
    const float* W      = (const float*)d_in[2];
    const float* a_src  = (const float*)d_in[3];
    const float* a_dst  = (const float*)d_in[4];
    const float* W_o    = (const float*)d_in[5];
    const float* ao_src = (const float*)d_in[6];
    const float* ao_dst = (const float*)d_in[7];
    float* out = (float*)d_out;

    char* wsp = (char*)d_ws;
    size_t off = 0;
    auto alloc = [&](size_t bytes) -> void* {
        void* p = wsp + off;
        off += (bytes + 255) & ~(size_t)255;
        return p;
    };
    unsigned* adj_bits = (unsigned*)alloc((size_t)N_NODES * NWORDS * 8);
    short*    Xbf   = (short*)alloc((size_t)N_NODES * FDIM * 2);
    short*    WF1   = (short*)alloc((size_t)H * 64 * D * 8 * 2);
    short*    WoF   = (short*)alloc((size_t)64 * D * 8 * 2);
    short*    WhB   = (short*)alloc((size_t)H * N_NODES * D * 2);
    float*    fs1   = (float*)alloc((size_t)H * N_NODES * 4);
    float*    fd1   = (float*)alloc((size_t)H * N_NODES * 4);
    unsigned* gme1  = (unsigned*)alloc((size_t)H * 4);
    float*    cm1   = (float*)alloc((size_t)H * D * 4);
    short*    num1  = (short*)alloc((size_t)8 * H * N_NODES * D * 2);
    float*    den1  = (float*)alloc((size_t)8 * H * N_NODES * 4);
    short*    hcat  = (short*)alloc((size_t)N_NODES * H * D * 2);
    short*    WhoB  = (short*)alloc((size_t)N_NODES * D * 2);
    float*    fs2   = (float*)alloc((size_t)N_NODES * 4);
    float*    fd2   = (float*)alloc((size_t)N_NODES * 4);
    unsigned* gme2  = (unsigned*)alloc(4);
    float*    cm2   = (float*)alloc((size_t)D * 4);
    short*    num2  = (short*)alloc((size_t)32 * N_NODES * D * 2);
    float*    den2  = (float*)alloc((size_t)32 * N_NODES * 4);

    k_pre  <<<dim3(1 + NB_BITS + NB_X + NB_W + NB_WO), dim3(256), 0, stream>>>(
        adj, x, W, W_o, adj_bits, Xbf, WF1, WoF, cm1, cm2, gme1, gme2);

    // layer 1 (8 heads, concat + ELU)
    k_gemm <<<dim3(N_NODES / 64, H), dim3(256), 0, stream>>>(Xbf, WF1, a_src, a_dst,
                                                             WhB, fs1, fd1, gme1, cm1);
    k_accum<<<dim3(N_NODES / 256, H, 8), dim3(256), 0, stream>>>(adj_bits, WhB, fs1, fd1, gme1,
                                                                 num1, den1, N_NODES / 8);
    k_post1<<<dim3(N_NODES / 64, H), dim3(256), 0, stream>>>(num1, den1, cm1, hcat);

    // layer 2 (single output head)
    k_gemm <<<dim3(N_NODES / 64, 1), dim3(256), 0, stream>>>(hcat, WoF, ao_src, ao_dst,
                                                             WhoB, fs2, fd2, gme2, cm2);
    k_accum<<<dim3(N_NODES / 256, 1, 32), dim3(256), 0, stream>>>(adj_bits, WhoB, fs2, fd2, gme2,
                                                                  num2, den2, N_NODES / 32);
    k_lsm  <<<dim3(N_NODES / 4), dim3(256), 0, stream>>>(num2, den2, cm2, out);
}

// Round 2
// 201.107 us; speedup vs baseline: 1.0179x; 1.0118x over previous
//
#include <hip/hip_runtime.h>
#include <hip/hip_bf16.h>
#include <math.h>

#define N_NODES 4096
#define FDIM 512            // K of both GEMMs (F_in = H*D = 512)
#define D 64
#define H 8
#define NWORDS (N_NODES / 64)

typedef __attribute__((ext_vector_type(8))) short bf16x8;      // raw 16B of halfwords
typedef __attribute__((ext_vector_type(4))) float f32x4;
typedef __attribute__((ext_vector_type(8))) _Float16 f16x8;    // MFMA f16 operand
typedef __attribute__((ext_vector_type(2))) _Float16 f16x2;    // packed-pair math
typedef __attribute__((ext_vector_type(4))) unsigned int u32x4;

__device__ inline short f2h(float x) {                         // f32->f16 RNE
    _Float16 h = (_Float16)x;
    return __builtin_bit_cast(short, h);
}
__device__ inline float h2f(unsigned short u) {
    return (float)__builtin_bit_cast(_Float16, u);
}
__device__ inline f16x2 bcH(unsigned int u) { return __builtin_bit_cast(f16x2, u); }

__device__ inline int sext_bit(unsigned int v, int j) {        // all-ones iff bit j set
#if defined(__has_builtin) && __has_builtin(__builtin_amdgcn_sbfe)
    return __builtin_amdgcn_sbfe((int)v, j, 1);
#else
    return ((int)(v << (31 - j))) >> 31;
#endif
}

// monotonic float<->uint encoding so unsigned atomicMax == float max
__device__ inline unsigned fenc(float f) {
    unsigned u = __builtin_bit_cast(unsigned, f);
    return (u & 0x80000000u) ? ~u : (u | 0x80000000u);
}
__device__ inline float fdec(unsigned e) {
    unsigned u = (e & 0x80000000u) ? (e & 0x7FFFFFFFu) : ~e;
    return __builtin_bit_cast(float, u);
}

// async global->LDS 16B copy (DMA). LDS dst must be wave-uniform base + lane*16.
__device__ inline void gl2lds16(const void* g, void* l) {
#if defined(__has_builtin) && __has_builtin(__builtin_amdgcn_global_load_lds)
    __builtin_amdgcn_global_load_lds(
        (const __attribute__((address_space(1))) unsigned int*)g,
        (__attribute__((address_space(3))) unsigned int*)l, 16, 0, 0);
#else
    *(uint4*)l = *(const uint4*)g;
#endif
}

// ---------------------------------------------------------------- fused preprocessing
// band 0: zero cm/gmax; bands: adj->bits (8/thread, int4 loads) | X->f16 (4/thread) | W | W_o
#define NB_BITS (N_NODES * N_NODES / 2048)     // 8 adj per thread
#define NB_X    (N_NODES * FDIM / 1024)        // 4 floats per thread
#define NB_W    (H * FDIM * D / 256)
#define NB_WO   (FDIM * D / 256)
__global__ void k_pre(const int* __restrict__ adj, const float* __restrict__ x,
                      const float* __restrict__ W, const float* __restrict__ Wo,
                      unsigned int* __restrict__ bits32, short* __restrict__ Xbf,
                      short* __restrict__ WF, short* __restrict__ WoF,
                      float* __restrict__ cm1, float* __restrict__ cm2,
                      unsigned* __restrict__ gmaxe1, unsigned* __restrict__ gmaxe2) {
    const int b = blockIdx.x, t = threadIdx.x;
    if (b == 0) {
        for (int i = t; i < H * D; i += 256) cm1[i] = 0.f;
        if (t < D) cm2[t] = 0.f;
        if (t < H) gmaxe1[t] = 0u;
        if (t == 0) gmaxe2[0] = 0u;
        return;
    }
    if (b < 1 + NB_BITS) {
        const int tid  = (b - 1) * 256 + t;     // one byte (8 adj) per thread
        const size_t e0 = (size_t)tid * 8;
        int4 a0 = *(const int4*)&adj[e0];
        int4 a1 = *(const int4*)&adj[e0 + 4];
        unsigned by = (unsigned)(a0.x != 0)       | ((unsigned)(a0.y != 0) << 1)
                    | ((unsigned)(a0.z != 0) << 2) | ((unsigned)(a0.w != 0) << 3)
                    | ((unsigned)(a1.x != 0) << 4) | ((unsigned)(a1.y != 0) << 5)
                    | ((unsigned)(a1.z != 0) << 6) | ((unsigned)(a1.w != 0) << 7);
        unsigned v = by | (__shfl_xor((int)by, 1) << 8);
        v = v | ((unsigned)__shfl_xor((int)v, 2) << 16);
        if ((t & 3) == 0) bits32[tid >> 2] = v;
        return;
    }
    if (b < 1 + NB_BITS + NB_X) {
        const size_t i4 = ((size_t)(b - 1 - NB_BITS) * 256 + t) * 4;
        float4 v = *(const float4*)&x[i4];
        ushort4 o;
        o.x = (unsigned short)f2h(v.x); o.y = (unsigned short)f2h(v.y);
        o.z = (unsigned short)f2h(v.z); o.w = (unsigned short)f2h(v.w);
        *(ushort4*)&Xbf[i4] = o;
        return;
    }
    if (b < 1 + NB_BITS + NB_X + NB_W) {
        const size_t idx = (size_t)(b - 1 - NB_BITS - NB_X) * 256 + t;   // (h*512+k)*64+d
        const int d = idx & 63;
        const int k = (int)(idx >> 6) & 511;
        const int h = (int)(idx >> 15);
        WF[(((size_t)h * 64 + (k >> 3)) * 64 + d) * 8 + (k & 7)] = f2h(W[idx]);
        return;
    }
    {
        const size_t idx = (size_t)(b - 1 - NB_BITS - NB_X - NB_W) * 256 + t;  // k*64+d
        const int d = idx & 63;
        const int k = (int)(idx >> 6);
        WoF[(((size_t)(k >> 3)) * 64 + d) * 8 + (k & 7)] = f2h(Wo[idx]);
    }
}

// ---------------------------------------------------------------- MFMA GEMM [N,512]@[512,64] per head
// f16 A from global; writes f16 frag copy of C, fused fs/fd row dot-products,
// and fused per-head stats: gmax(fd) via encoded atomicMax, colmean via atomicAdd.
__global__ void __launch_bounds__(256) k_gemm(
    const short* __restrict__ Xbf, const short* __restrict__ WF,
    const float* __restrict__ av, const float* __restrict__ bv,
    short* __restrict__ WBout, float* __restrict__ fs, float* __restrict__ fd,
    unsigned* __restrict__ gmaxe, float* __restrict__ cm) {
    const int h  = blockIdx.y;
    const int i0 = blockIdx.x * 64;
    const int t = threadIdx.x, w = t >> 6, lane = t & 63;
    const int li = lane & 15, quad = lane >> 4, k0 = quad * 8;
    const int row_a = i0 + w * 16 + li;
    const short* __restrict__ Xr  = Xbf + (size_t)row_a * FDIM;
    const short* __restrict__ WFh = WF + (size_t)h * 64 * D * 8;

    f32x4 c0 = {0.f, 0.f, 0.f, 0.f}, c1 = c0, c2 = c0, c3 = c0;
    #pragma unroll 4
    for (int kt = 0; kt < FDIM; kt += 32) {
        f16x8 a = __builtin_bit_cast(f16x8, *(const bf16x8*)&Xr[kt + k0]);
        const short* bb = WFh + (size_t)((kt >> 3) + quad) * (D * 8) + li * 8;
        f16x8 b0 = __builtin_bit_cast(f16x8, *(const bf16x8*)(bb));
        f16x8 b1 = __builtin_bit_cast(f16x8, *(const bf16x8*)(bb + 128));
        f16x8 b2 = __builtin_bit_cast(f16x8, *(const bf16x8*)(bb + 256));
        f16x8 b3 = __builtin_bit_cast(f16x8, *(const bf16x8*)(bb + 384));
        c0 = __builtin_amdgcn_mfma_f32_16x16x32_f16(a, b0, c0, 0, 0, 0);
        c1 = __builtin_amdgcn_mfma_f32_16x16x32_f16(a, b1, c1, 0, 0, 0);
        c2 = __builtin_amdgcn_mfma_f32_16x16x32_f16(a, b2, c2, 0, 0, 0);
        c3 = __builtin_amdgcn_mfma_f32_16x16x32_f16(a, b3, c3, 0, 0, 0);
    }
    float av4[4], bv4[4];
    #pragma unroll
    for (int t4 = 0; t4 < 4; ++t4) {
        av4[t4] = av[h * D + t4 * 16 + li];
        bv4[t4] = bv[h * D + t4 * 16 + li];
    }
    float tiles[4][4];
    #pragma unroll
    for (int r = 0; r < 4; ++r) { tiles[0][r] = c0[r]; tiles[1][r] = c1[r]; tiles[2][r] = c2[r]; tiles[3][r] = c3[r]; }

    __shared__ float csum[4][64];
    __shared__ float red[4];
    float fdmax = -INFINITY;
    float s4[4] = {0.f, 0.f, 0.f, 0.f};

    #pragma unroll
    for (int r = 0; r < 4; ++r) {
        const int row = i0 + w * 16 + quad * 4 + r;
        float pa = 0.f, pb = 0.f;
        #pragma unroll
        for (int t4 = 0; t4 < 4; ++t4) {
            const float v = tiles[t4][r];
            const int d = t4 * 16 + li;
            WBout[((size_t)h * (N_NODES / 8) + (row >> 3)) * (D * 8) + d * 8 + (row & 7)] = f2h(v);
            pa += v * av4[t4];
            pb += v * bv4[t4];
            s4[t4] += v;
        }
        #pragma unroll
        for (int off = 1; off < 16; off <<= 1) {
            pa += __shfl_xor(pa, off);
            pb += __shfl_xor(pb, off);
        }
        if (li == 0) {
            fs[(size_t)h * N_NODES + row] = pa;
            fd[(size_t)h * N_NODES + row] = pb;
        }
        fdmax = fmaxf(fdmax, pb);
    }
    fdmax = fmaxf(fdmax, __shfl_xor(fdmax, 16));
    fdmax = fmaxf(fdmax, __shfl_xor(fdmax, 32));
    if (lane == 0) red[w] = fdmax;
    #pragma unroll
    for (int t4 = 0; t4 < 4; ++t4) {
        s4[t4] += __shfl_xor(s4[t4], 16);
        s4[t4] += __shfl_xor(s4[t4], 32);
    }
    if (quad == 0)
        #pragma unroll
        for (int t4 = 0; t4 < 4; ++t4) csum[w][t4 * 16 + li] = s4[t4];
    __syncthreads();
    if (t == 0)
        atomicMax(gmaxe + h, fenc(fmaxf(fmaxf(red[0], red[1]), fmaxf(red[2], red[3]))));
    if (t < 64)
        atomicAdd(&cm[h * D + t],
                  (csum[0][t] + csum[1][t] + csum[2][t] + csum[3][t]) * (1.f / (float)N_NODES));
}

// ---------------------------------------------------------------- MFMA attention aggregation (j-split)
// 256 i-rows/block, 64 rows/wave. B-tile (16 KB) DMA'd to LDS, double-buffered,
// counted-vmcnt pipeline (unchanged from prev round). NEW: all data f16, and the
// A-fragment is built with packed-f16 math: per 2 elems {v_pk_mul_f16,
// v_pk_max_f16, 2x v_bfe_i32, v_perm, v_and} — results land directly in the
// MFMA pair layout (j=2d lo-half, j=2d+1 hi-half), so the old per-element
// f32 mul/max/bfe/and + 4 pack-perms (and the ev/gv unpack movs) are gone.
// E/G tables are packed f16 in LDS (1 KB each).
__global__ void __launch_bounds__(256, 3) k_accum(
    const unsigned int* __restrict__ bits32,
    const short* __restrict__ WB,
    const float* __restrict__ fsb, const float* __restrict__ fdb,
    const unsigned* __restrict__ gmaxe,
    short* __restrict__ num, float* __restrict__ den, int kslab) {

    __shared__ __align__(16) short Bt[2][16 * 64 * 8];   // 2 x 16 KB
    __shared__ __align__(16) short Esh[512];             // f16: exp(fd - gm), whole slab
    __shared__ __align__(16) short Gsh[512];             // f16: exp(0.2*(fd - gm))

    const int h = blockIdx.y, i0 = blockIdx.x * 256, slab = blockIdx.z;
    const int t = threadIdx.x, w = t >> 6, lane = t & 63;
    const int li = lane & 15, quad = lane >> 4, k0 = quad * 8;
    const size_t ho = (size_t)h * N_NODES;
    const float  gm = fdec(gmaxe[h]);
    const float* __restrict__ fd = fdb + ho;
    const short* __restrict__ Bh = WB + (size_t)h * (N_NODES / 8) * D * 8;

    const int k_beg = slab * kslab;
    const int ntile = kslab / 128;

    auto stage = [&](int buf, int jtile) {
        const short* src = Bh + (size_t)(jtile >> 3) * (D * 8);
        #pragma unroll
        for (int p = 0; p < 4; ++p)
            gl2lds16(src + (size_t)(p * 256 + t) * 8, &Bt[buf][(p * 256 + t) * 8]);
    };

    // ---- prologue: tile-0 bits, stage tile 0, EG table (packed f16), Rp, acc init
    int bito[4];
    #pragma unroll
    for (int f = 0; f < 4; ++f)
        bito[f] = (i0 + w * 64 + f * 16 + li) * (NWORDS * 2);
    uint4 bw[4];
    #pragma unroll
    for (int f = 0; f < 4; ++f)
        bw[f] = *(const uint4*)&bits32[(size_t)bito[f] + (k_beg >> 5)];
    stage(0, k_beg);
    {
        const int jj = t * 2;                 // whole-slab EG table, one shot
        if (jj < kslab) {
            float2 f2 = *(const float2*)&fd[k_beg + jj];
            f16x2 ep = {(_Float16)__expf(f2.x - gm), (_Float16)__expf(f2.y - gm)};
            f16x2 gp = {(_Float16)__expf(0.2f * (f2.x - gm)),
                        (_Float16)__expf(0.2f * (f2.y - gm))};
            *(f16x2*)&Esh[jj] = ep;
            *(f16x2*)&Gsh[jj] = gp;
        }
    }
    f16x2 Rp[4];
    #pragma unroll
    for (int f = 0; f < 4; ++f) {
        const float rv = __expf(-0.8f * (fsb[ho + i0 + w * 64 + f * 16 + li] + gm));
        const _Float16 rh = (_Float16)rv;
        Rp[f] = (f16x2){rh, rh};
    }

    f32x4 acc[4][4], c5[4];
    #pragma unroll
    for (int f = 0; f < 4; ++f) {
        #pragma unroll
        for (int q = 0; q < 4; ++q) acc[f][q] = (f32x4){0.f, 0.f, 0.f, 0.f};
        c5[f] = (f32x4){0.f, 0.f, 0.f, 0.f};
    }
    bf16x8 ones_;
    #pragma unroll
    for (int j = 0; j < 8; ++j) ones_[j] = (short)0x3C00;    // f16 1.0
    const f16x8 ones = __builtin_bit_cast(f16x8, ones_);

    __syncthreads();   // drains prologue vmcnt (stage0, bits0) + EG lds writes

    for (int tile = 0; tile < ntile; ++tile) {
        const int jt = k_beg + tile * 128;
        // b1: all waves finished compute(tile-1) -> buf[(tile+1)&1] is free
        __builtin_amdgcn_s_barrier();
        if (tile > 0) {
            #pragma unroll
            for (int f = 0; f < 4; ++f)
                bw[f] = *(const uint4*)&bits32[(size_t)bito[f] + (jt >> 5)];
        }
        if (tile + 1 < ntile) {
            stage((tile + 1) & 1, jt + 128);
            // outstanding: stage(t)[4] + bits(t)[4] + stage(t+1)[4] -> keep 4 newest
            asm volatile("s_waitcnt vmcnt(4)" ::: "memory");
        } else {
            asm volatile("s_waitcnt vmcnt(0)" ::: "memory");
        }
        // b2: every wave drained its stage(tile) -> buf[tile&1] fully written
        __builtin_amdgcn_s_barrier();

        const short* Bl = Bt[tile & 1];
        const short* Ee = Esh + tile * 128;
        const short* Gg = Gsh + tile * 128;
        #pragma unroll
        for (int s = 0; s < 4; ++s) {
            const uint4 Eu = *(const uint4*)&Ee[s * 32 + k0];   // 8 f16 (broadcast per quad)
            const uint4 Gu = *(const uint4*)&Gg[s * 32 + k0];
            f16x2 Ep[4] = {bcH(Eu.x), bcH(Eu.y), bcH(Eu.z), bcH(Eu.w)};
            f16x2 Gp[4] = {bcH(Gu.x), bcH(Gu.y), bcH(Gu.z), bcH(Gu.w)};
            const short* bb = Bl + (size_t)((s * 4 + quad) * 64 + li) * 8;
            f16x8 b0 = __builtin_bit_cast(f16x8, *(const bf16x8*)(bb));
            f16x8 b1 = __builtin_bit_cast(f16x8, *(const bf16x8*)(bb + 128));
            f16x8 b2 = __builtin_bit_cast(f16x8, *(const bf16x8*)(bb + 256));
            f16x8 b3 = __builtin_bit_cast(f16x8, *(const bf16x8*)(bb + 384));
            #pragma unroll
            for (int f = 0; f < 4; ++f) {
                const unsigned int wsel = (s == 0) ? bw[f].x : (s == 1) ? bw[f].y
                                        : (s == 2) ? bw[f].z : bw[f].w;
                const unsigned int byt = (wsel >> k0) & 0xFFu;
                u32x4 au;
                #pragma unroll
                for (int d2 = 0; d2 < 4; ++d2) {
                    // mask word: lo16 = sext(bit 2d), hi16 = sext(bit 2d+1)
                    const unsigned mw = (unsigned)__builtin_amdgcn_perm(
                        (unsigned)sext_bit(byt, 2 * d2 + 1),
                        (unsigned)sext_bit(byt, 2 * d2), 0x05040100u);
                    const f16x2 tv = Gp[d2] * Rp[f];                       // v_pk_mul_f16
                    const f16x2 pv = __builtin_elementwise_max(Ep[d2], tv); // v_pk_max_f16
                    au[d2] = __builtin_bit_cast(unsigned, pv) & mw;
                }
                const f16x8 a = __builtin_bit_cast(f16x8, au);
                __builtin_amdgcn_s_setprio(1);
                acc[f][0] = __builtin_amdgcn_mfma_f32_16x16x32_f16(a, b0, acc[f][0], 0, 0, 0);
                acc[f][1] = __builtin_amdgcn_mfma_f32_16x16x32_f16(a, b1, acc[f][1], 0, 0, 0);
                acc[f][2] = __builtin_amdgcn_mfma_f32_16x16x32_f16(a, b2, acc[f][2], 0, 0, 0);
                acc[f][3] = __builtin_amdgcn_mfma_f32_16x16x32_f16(a, b3, acc[f][3], 0, 0, 0);
                c5[f]     = __builtin_amdgcn_mfma_f32_16x16x32_f16(a, ones, c5[f], 0, 0, 0);
                __builtin_amdgcn_s_setprio(0);
            }
        }
    }

    const size_t so = (size_t)(slab * gridDim.y + h);
    #pragma unroll
    for (int f = 0; f < 4; ++f) {
        #pragma unroll
        for (int t4 = 0; t4 < 4; ++t4)
            #pragma unroll
            for (int r = 0; r < 4; ++r) {
                const int row = i0 + w * 64 + f * 16 + quad * 4 + r;
                num[(so * N_NODES + row) * D + t4 * 16 + li] = f2h(acc[f][t4][r]);
            }
        if (li == 0)
            #pragma unroll
            for (int r = 0; r < 4; ++r)
                den[so * N_NODES + i0 + w * 64 + f * 16 + quad * 4 + r] = c5[f][r];
    }
}

// ---------------------------------------------------------------- layer-1 combine (JS=8): norm+fallback+ELU, f16 out
__global__ void k_post1(const short* __restrict__ num, const float* __restrict__ den,
                        const float* __restrict__ colmean, short* __restrict__ hcat) {
    const int h   = blockIdx.y;
    const int i0  = blockIdx.x * 64;
    const int t   = threadIdx.x;
    const int row = i0 + (t >> 2);
    const int cb  = (t & 3) * 16;
    const size_t HN = (size_t)gridDim.y * N_NODES;
    const size_t r0 = (size_t)h * N_NODES + row;
    float dsum = 0.f;
    #pragma unroll
    for (int s = 0; s < 8; ++s) dsum += den[s * HN + r0];
    const bool  uni  = !(dsum > 0.f);
    const float linv = uni ? 0.f : 1.f / dsum;
    #pragma unroll
    for (int c = 0; c < 4; ++c) {
        const int col = cb + c * 4;
        float4 v = {0.f, 0.f, 0.f, 0.f};
        #pragma unroll
        for (int s = 0; s < 8; ++s) {
            ushort4 a = *(const ushort4*)&num[(s * HN + r0) * D + col];
            v.x += h2f(a.x); v.y += h2f(a.y); v.z += h2f(a.z); v.w += h2f(a.w);
        }
        v.x *= linv; v.y *= linv; v.z *= linv; v.w *= linv;
        if (uni) v = *(const float4*)&colmean[h * D + col];
        v.x = v.x > 0.f ? v.x : __expf(v.x) - 1.f;
        v.y = v.y > 0.f ? v.y : __expf(v.y) - 1.f;
        v.z = v.z > 0.f ? v.z : __expf(v.z) - 1.f;
        v.w = v.w > 0.f ? v.w : __expf(v.w) - 1.f;
        ushort4 o;
        o.x = (unsigned short)f2h(v.x); o.y = (unsigned short)f2h(v.y);
        o.z = (unsigned short)f2h(v.z); o.w = (unsigned short)f2h(v.w);
        *(ushort4*)&hcat[(size_t)row * (H * D) + h * D + col] = o;
    }
}

// ---------------------------------------------------------------- layer-2 combine (JS=32) + ELU + log_softmax
__global__ void k_lsm(const short* __restrict__ num, const float* __restrict__ den,
                      const float* __restrict__ cm, float* __restrict__ out) {
    const int n    = blockIdx.x * 4 + (threadIdx.x >> 6);
    const int lane = threadIdx.x & 63;
    float v = 0.f, ds = 0.f;
    #pragma unroll
    for (int s = 0; s < 32; ++s)
        v += h2f((unsigned short)num[((size_t)s * N_NODES + n) * D + lane]);
    #pragma unroll
    for (int s = 0; s < 32; ++s) ds += den[(size_t)s * N_NODES + n];
    v = (ds > 0.f) ? v / ds : cm[lane];
    v = v > 0.f ? v : __expf(v) - 1.f;
    float mx = v;
    #pragma unroll
    for (int off = 32; off > 0; off >>= 1) mx = fmaxf(mx, __shfl_xor(mx, off));
    float ex = __expf(v - mx);
    float sum = ex;
    #pragma unroll
    for (int off = 32; off > 0; off >>= 1) sum += __shfl_xor(sum, off);
    out[(size_t)n * D + lane] = (v - mx) - __logf(sum);
}

// ----------------------------------------------------------------
extern "C" void kernel_launch(void* const* d_in, const int* in_sizes, int n_in,
                              void* d_out, int out_size, void* d_ws, size_t ws_size,
                              hipStream_t stream) {
    const float* x      = (const float*)d_in[0];
    const int*   adj    = (const int*)d_in[1];
    const float* W      = (const float*)d_in[2];
    const float* a_src  = (const float*)d_in[3];
    const float* a_dst  = (const float*)d_in[4];
    const float* W_o    = (const float*)d_in[5];
    const float* ao_src = (const float*)d_in[6];
    const float* ao_dst = (const float*)d_in[7];
    float* out = (float*)d_out;

    char* wsp = (char*)d_ws;
    size_t off = 0;
    auto alloc = [&](size_t bytes) -> void* {
        void* p = wsp + off;
        off += (bytes + 255) & ~(size_t)255;
        return p;
    };
    unsigned* adj_bits = (unsigned*)alloc((size_t)N_NODES * NWORDS * 8);
    short*    Xbf   = (short*)alloc((size_t)N_NODES * FDIM * 2);
    short*    WF1   = (short*)alloc((size_t)H * 64 * D * 8 * 2);
    short*    WoF   = (short*)alloc((size_t)64 * D * 8 * 2);
    short*    WhB   = (short*)alloc((size_t)H * N_NODES * D * 2);
    float*    fs1   = (float*)alloc((size_t)H * N_NODES * 4);
    float*    fd1   = (float*)alloc((size_t)H * N_NODES * 4);
    unsigned* gme1  = (unsigned*)alloc((size_t)H * 4);
    float*    cm1   = (float*)alloc((size_t)H * D * 4);
    short*    num1  = (short*)alloc((size_t)8 * H * N_NODES * D * 2);
    float*    den1  = (float*)alloc((size_t)8 * H * N_NODES * 4);
    short*    hcat  = (short*)alloc((size_t)N_NODES * H * D * 2);
    short*    WhoB  = (short*)alloc((size_t)N_NODES * D * 2);
    float*    fs2   = (float*)alloc((size_t)N_NODES * 4);
    float*    fd2   = (float*)alloc((size_t)N_NODES * 4);
    unsigned* gme2  = (unsigned*)alloc(4);
    float*    cm2   = (float*)alloc((size_t)D * 4);
    short*    num2  = (short*)alloc((size_t)32 * N_NODES * D * 2);
    float*    den2  = (float*)alloc((size_t)32 * N_NODES * 4);

    k_pre  <<<dim3(1 + NB_BITS + NB_X + NB_W + NB_WO), dim3(256), 0, stream>>>(
        adj, x, W, W_o, adj_bits, Xbf, WF1, WoF, cm1, cm2, gme1, gme2);

    // layer 1 (8 heads, concat + ELU)
    k_gemm <<<dim3(N_NODES / 64, H), dim3(256), 0, stream>>>(Xbf, WF1, a_src, a_dst,
                                                             WhB, fs1, fd1, gme1, cm1);
    k_accum<<<dim3(N_NODES / 256, H, 8), dim3(256), 0, stream>>>(adj_bits, WhB, fs1, fd1, gme1,
                                                                 num1, den1, N_NODES / 8);
    k_post1<<<dim3(N_NODES / 64, H), dim3(256), 0, stream>>>(num1, den1, cm1, hcat);

    // layer 2 (single output head)
    k_gemm <<<dim3(N_NODES / 64, 1), dim3(256), 0, stream>>>(hcat, WoF, ao_src, ao_dst,
                                                             WhoB, fs2, fd2, gme2, cm2);
    k_accum<<<dim3(N_NODES / 256, 1, 32), dim3(256), 0, stream>>>(adj_bits, WhoB, fs2, fd2, gme2,
                                                                  num2, den2, N_NODES / 32);
    k_lsm  <<<dim3(N_NODES / 4), dim3(256), 0, stream>>>(num2, den2, cm2, out);
}

// Round 3
// 195.505 us; speedup vs baseline: 1.0471x; 1.0287x over previous
//
#include <hip/hip_runtime.h>
#include <hip/hip_bf16.h>
#include <math.h>

#define N_NODES 4096
#define FDIM 512            // K of both GEMMs (F_in = H*D = 512)
#define D 64
#define H 8
#define NWORDS (N_NODES / 64)
#define S1 4                // layer-1 j-slabs  (32 rowblocks * 8 heads * 4 = 1024 = 4 blocks/CU exactly)
#define S2 16               // layer-2 j-slabs  (32 rowblocks * 16 = 512 blocks)

typedef __attribute__((ext_vector_type(8))) short bf16x8;      // raw 16B of halfwords
typedef __attribute__((ext_vector_type(4))) float f32x4;
typedef __attribute__((ext_vector_type(8))) _Float16 f16x8;    // MFMA f16 operand
typedef __attribute__((ext_vector_type(2))) _Float16 f16x2;    // packed-pair math
typedef __attribute__((ext_vector_type(4))) unsigned int u32x4;

__device__ inline short f2h(float x) {                         // f32->f16 RNE
    _Float16 h = (_Float16)x;
    return __builtin_bit_cast(short, h);
}
__device__ inline float h2f(unsigned short u) {
    return (float)__builtin_bit_cast(_Float16, u);
}
__device__ inline f16x2 bcH(unsigned int u) { return __builtin_bit_cast(f16x2, u); }

__device__ inline int sext_bit(unsigned int v, int j) {        // all-ones iff bit j set
#if defined(__has_builtin) && __has_builtin(__builtin_amdgcn_sbfe)
    return __builtin_amdgcn_sbfe((int)v, j, 1);
#else
    return ((int)(v << (31 - j))) >> 31;
#endif
}

// monotonic float<->uint encoding so unsigned atomicMax == float max
__device__ inline unsigned fenc(float f) {
    unsigned u = __builtin_bit_cast(unsigned, f);
    return (u & 0x80000000u) ? ~u : (u | 0x80000000u);
}
__device__ inline float fdec(unsigned e) {
    unsigned u = (e & 0x80000000u) ? (e & 0x7FFFFFFFu) : ~e;
    return __builtin_bit_cast(float, u);
}

// async global->LDS 16B copy (DMA). LDS dst must be wave-uniform base + lane*16.
__device__ inline void gl2lds16(const void* g, void* l) {
#if defined(__has_builtin) && __has_builtin(__builtin_amdgcn_global_load_lds)
    __builtin_amdgcn_global_load_lds(
        (const __attribute__((address_space(1))) unsigned int*)g,
        (__attribute__((address_space(3))) unsigned int*)l, 16, 0, 0);
#else
    *(uint4*)l = *(const uint4*)g;
#endif
}

// ---------------------------------------------------------------- fused preprocessing
// band 0: zero cm/gmax; bands: adj->bits (8/thread, int4 loads) | X->f16 (4/thread) | W | W_o
#define NB_BITS (N_NODES * N_NODES / 2048)     // 8 adj per thread
#define NB_X    (N_NODES * FDIM / 1024)        // 4 floats per thread
#define NB_W    (H * FDIM * D / 256)
#define NB_WO   (FDIM * D / 256)
__global__ void k_pre(const int* __restrict__ adj, const float* __restrict__ x,
                      const float* __restrict__ W, const float* __restrict__ Wo,
                      unsigned int* __restrict__ bits32, short* __restrict__ Xbf,
                      short* __restrict__ WF, short* __restrict__ WoF,
                      float* __restrict__ cm1, float* __restrict__ cm2,
                      unsigned* __restrict__ gmaxe1, unsigned* __restrict__ gmaxe2) {
    const int b = blockIdx.x, t = threadIdx.x;
    if (b == 0) {
        for (int i = t; i < H * D; i += 256) cm1[i] = 0.f;
        if (t < D) cm2[t] = 0.f;
        if (t < H) gmaxe1[t] = 0u;
        if (t == 0) gmaxe2[0] = 0u;
        return;
    }
    if (b < 1 + NB_BITS) {
        const int tid  = (b - 1) * 256 + t;     // one byte (8 adj) per thread
        const size_t e0 = (size_t)tid * 8;
        int4 a0 = *(const int4*)&adj[e0];
        int4 a1 = *(const int4*)&adj[e0 + 4];
        unsigned by = (unsigned)(a0.x != 0)       | ((unsigned)(a0.y != 0) << 1)
                    | ((unsigned)(a0.z != 0) << 2) | ((unsigned)(a0.w != 0) << 3)
                    | ((unsigned)(a1.x != 0) << 4) | ((unsigned)(a1.y != 0) << 5)
                    | ((unsigned)(a1.z != 0) << 6) | ((unsigned)(a1.w != 0) << 7);
        unsigned v = by | (__shfl_xor((int)by, 1) << 8);
        v = v | ((unsigned)__shfl_xor((int)v, 2) << 16);
        if ((t & 3) == 0) bits32[tid >> 2] = v;
        return;
    }
    if (b < 1 + NB_BITS + NB_X) {
        const size_t i4 = ((size_t)(b - 1 - NB_BITS) * 256 + t) * 4;
        float4 v = *(const float4*)&x[i4];
        ushort4 o;
        o.x = (unsigned short)f2h(v.x); o.y = (unsigned short)f2h(v.y);
        o.z = (unsigned short)f2h(v.z); o.w = (unsigned short)f2h(v.w);
        *(ushort4*)&Xbf[i4] = o;
        return;
    }
    if (b < 1 + NB_BITS + NB_X + NB_W) {
        const size_t idx = (size_t)(b - 1 - NB_BITS - NB_X) * 256 + t;   // (h*512+k)*64+d
        const int d = idx & 63;
        const int k = (int)(idx >> 6) & 511;
        const int h = (int)(idx >> 15);
        WF[(((size_t)h * 64 + (k >> 3)) * 64 + d) * 8 + (k & 7)] = f2h(W[idx]);
        return;
    }
    {
        const size_t idx = (size_t)(b - 1 - NB_BITS - NB_X - NB_W) * 256 + t;  // k*64+d
        const int d = idx & 63;
        const int k = (int)(idx >> 6);
        WoF[(((size_t)(k >> 3)) * 64 + d) * 8 + (k & 7)] = f2h(Wo[idx]);
    }
}

// ---------------------------------------------------------------- MFMA GEMM [N,512]@[512,64] per head
// f16 A from global; writes f16 frag copy of C, fused fs/fd row dot-products,
// and fused per-head stats: gmax(fd) via encoded atomicMax, colmean via atomicAdd.
__global__ void __launch_bounds__(256) k_gemm(
    const short* __restrict__ Xbf, const short* __restrict__ WF,
    const float* __restrict__ av, const float* __restrict__ bv,
    short* __restrict__ WBout, float* __restrict__ fs, float* __restrict__ fd,
    unsigned* __restrict__ gmaxe, float* __restrict__ cm) {
    const int h  = blockIdx.y;
    const int i0 = blockIdx.x * 64;
    const int t = threadIdx.x, w = t >> 6, lane = t & 63;
    const int li = lane & 15, quad = lane >> 4, k0 = quad * 8;
    const int row_a = i0 + w * 16 + li;
    const short* __restrict__ Xr  = Xbf + (size_t)row_a * FDIM;
    const short* __restrict__ WFh = WF + (size_t)h * 64 * D * 8;

    f32x4 c0 = {0.f, 0.f, 0.f, 0.f}, c1 = c0, c2 = c0, c3 = c0;
    #pragma unroll 4
    for (int kt = 0; kt < FDIM; kt += 32) {
        f16x8 a = __builtin_bit_cast(f16x8, *(const bf16x8*)&Xr[kt + k0]);
        const short* bb = WFh + (size_t)((kt >> 3) + quad) * (D * 8) + li * 8;
        f16x8 b0 = __builtin_bit_cast(f16x8, *(const bf16x8*)(bb));
        f16x8 b1 = __builtin_bit_cast(f16x8, *(const bf16x8*)(bb + 128));
        f16x8 b2 = __builtin_bit_cast(f16x8, *(const bf16x8*)(bb + 256));
        f16x8 b3 = __builtin_bit_cast(f16x8, *(const bf16x8*)(bb + 384));
        c0 = __builtin_amdgcn_mfma_f32_16x16x32_f16(a, b0, c0, 0, 0, 0);
        c1 = __builtin_amdgcn_mfma_f32_16x16x32_f16(a, b1, c1, 0, 0, 0);
        c2 = __builtin_amdgcn_mfma_f32_16x16x32_f16(a, b2, c2, 0, 0, 0);
        c3 = __builtin_amdgcn_mfma_f32_16x16x32_f16(a, b3, c3, 0, 0, 0);
    }
    float av4[4], bv4[4];
    #pragma unroll
    for (int t4 = 0; t4 < 4; ++t4) {
        av4[t4] = av[h * D + t4 * 16 + li];
        bv4[t4] = bv[h * D + t4 * 16 + li];
    }
    float tiles[4][4];
    #pragma unroll
    for (int r = 0; r < 4; ++r) { tiles[0][r] = c0[r]; tiles[1][r] = c1[r]; tiles[2][r] = c2[r]; tiles[3][r] = c3[r]; }

    __shared__ float csum[4][64];
    __shared__ float red[4];
    float fdmax = -INFINITY;
    float s4[4] = {0.f, 0.f, 0.f, 0.f};

    #pragma unroll
    for (int r = 0; r < 4; ++r) {
        const int row = i0 + w * 16 + quad * 4 + r;
        float pa = 0.f, pb = 0.f;
        #pragma unroll
        for (int t4 = 0; t4 < 4; ++t4) {
            const float v = tiles[t4][r];
            const int d = t4 * 16 + li;
            WBout[((size_t)h * (N_NODES / 8) + (row >> 3)) * (D * 8) + d * 8 + (row & 7)] = f2h(v);
            pa += v * av4[t4];
            pb += v * bv4[t4];
            s4[t4] += v;
        }
        #pragma unroll
        for (int off = 1; off < 16; off <<= 1) {
            pa += __shfl_xor(pa, off);
            pb += __shfl_xor(pb, off);
        }
        if (li == 0) {
            fs[(size_t)h * N_NODES + row] = pa;
            fd[(size_t)h * N_NODES + row] = pb;
        }
        fdmax = fmaxf(fdmax, pb);
    }
    fdmax = fmaxf(fdmax, __shfl_xor(fdmax, 16));
    fdmax = fmaxf(fdmax, __shfl_xor(fdmax, 32));
    if (lane == 0) red[w] = fdmax;
    #pragma unroll
    for (int t4 = 0; t4 < 4; ++t4) {
        s4[t4] += __shfl_xor(s4[t4], 16);
        s4[t4] += __shfl_xor(s4[t4], 32);
    }
    if (quad == 0)
        #pragma unroll
        for (int t4 = 0; t4 < 4; ++t4) csum[w][t4 * 16 + li] = s4[t4];
    __syncthreads();
    if (t == 0)
        atomicMax(gmaxe + h, fenc(fmaxf(fmaxf(red[0], red[1]), fmaxf(red[2], red[3]))));
    if (t < 64)
        atomicAdd(&cm[h * D + t],
                  (csum[0][t] + csum[1][t] + csum[2][t] + csum[3][t]) * (1.f / (float)N_NODES));
}

// ---------------------------------------------------------------- MFMA attention aggregation (j-split)
// GRID-BALANCED build: 128-thread blocks (2 waves x 64 rows), LDS = 32KB Bt +
// 4KB EG = 36864 B -> 4 blocks/CU (LDS-capped). L1 grid = 32 x 8 x S1(4) =
// 1024 blocks = 256 CU x 4 EXACTLY -> one scheduling round, no tail.
// (Previous 256-thread/3-blocks-per-CU config ran 1024 blocks in 2 rounds at
// 67% utilization — occupancy and VALU fixes couldn't show through that.)
// Counted-vmcnt pipeline kept: stage = 8 DMA loads/thread, bits = 4 loads,
// so steady-state wait is vmcnt(8) (next tile's 8 stays in flight).
__global__ void __launch_bounds__(128, 2) k_accum(
    const unsigned int* __restrict__ bits32,
    const short* __restrict__ WB,
    const float* __restrict__ fsb, const float* __restrict__ fdb,
    const unsigned* __restrict__ gmaxe,
    short* __restrict__ num, float* __restrict__ den, int kslab) {

    __shared__ __align__(16) short Bt[2][16 * 64 * 8];   // 2 x 16 KB
    __shared__ __align__(16) short Esh[1024];            // f16: exp(fd - gm), whole slab
    __shared__ __align__(16) short Gsh[1024];            // f16: exp(0.2*(fd - gm))

    const int h = blockIdx.y, i0 = blockIdx.x * 128, slab = blockIdx.z;
    const int t = threadIdx.x, w = t >> 6, lane = t & 63;
    const int li = lane & 15, quad = lane >> 4, k0 = quad * 8;
    const size_t ho = (size_t)h * N_NODES;
    const float  gm = fdec(gmaxe[h]);
    const float* __restrict__ fd = fdb + ho;
    const short* __restrict__ Bh = WB + (size_t)h * (N_NODES / 8) * D * 8;

    const int k_beg = slab * kslab;
    const int ntile = kslab / 128;

    auto stage = [&](int buf, int jtile) {
        const short* src = Bh + (size_t)(jtile >> 3) * (D * 8);
        #pragma unroll
        for (int p = 0; p < 8; ++p)
            gl2lds16(src + (size_t)(p * 128 + t) * 8, &Bt[buf][(p * 128 + t) * 8]);
    };

    // ---- prologue: tile-0 bits, stage tile 0, EG table (packed f16), Rp, acc init
    int bito[4];
    #pragma unroll
    for (int f = 0; f < 4; ++f)
        bito[f] = (i0 + w * 64 + f * 16 + li) * (NWORDS * 2);
    uint4 bw[4];
    #pragma unroll
    for (int f = 0; f < 4; ++f)
        bw[f] = *(const uint4*)&bits32[(size_t)bito[f] + (k_beg >> 5)];
    stage(0, k_beg);
    for (int jj = t * 2; jj < kslab; jj += 256) {        // whole-slab EG table
        float2 f2 = *(const float2*)&fd[k_beg + jj];
        f16x2 ep = {(_Float16)__expf(f2.x - gm), (_Float16)__expf(f2.y - gm)};
        f16x2 gp = {(_Float16)__expf(0.2f * (f2.x - gm)),
                    (_Float16)__expf(0.2f * (f2.y - gm))};
        *(f16x2*)&Esh[jj] = ep;
        *(f16x2*)&Gsh[jj] = gp;
    }
    f16x2 Rp[4];
    #pragma unroll
    for (int f = 0; f < 4; ++f) {
        const float rv = __expf(-0.8f * (fsb[ho + i0 + w * 64 + f * 16 + li] + gm));
        const _Float16 rh = (_Float16)rv;
        Rp[f] = (f16x2){rh, rh};
    }

    f32x4 acc[4][4], c5[4];
    #pragma unroll
    for (int f = 0; f < 4; ++f) {
        #pragma unroll
        for (int q = 0; q < 4; ++q) acc[f][q] = (f32x4){0.f, 0.f, 0.f, 0.f};
        c5[f] = (f32x4){0.f, 0.f, 0.f, 0.f};
    }
    bf16x8 ones_;
    #pragma unroll
    for (int j = 0; j < 8; ++j) ones_[j] = (short)0x3C00;    // f16 1.0
    const f16x8 ones = __builtin_bit_cast(f16x8, ones_);

    __syncthreads();   // drains prologue vmcnt (stage0, bits0) + EG lds writes

    for (int tile = 0; tile < ntile; ++tile) {
        const int jt = k_beg + tile * 128;
        // b1: all waves finished compute(tile-1) -> buf[(tile+1)&1] is free
        __builtin_amdgcn_s_barrier();
        if (tile > 0) {
            #pragma unroll
            for (int f = 0; f < 4; ++f)
                bw[f] = *(const uint4*)&bits32[(size_t)bito[f] + (jt >> 5)];
        }
        if (tile + 1 < ntile) {
            stage((tile + 1) & 1, jt + 128);
            // outstanding: stage(t)[8] + bits(t)[4] + stage(t+1)[8] -> keep 8 newest
            asm volatile("s_waitcnt vmcnt(8)" ::: "memory");
        } else {
            asm volatile("s_waitcnt vmcnt(0)" ::: "memory");
        }
        // b2: every wave drained its stage(tile) -> buf[tile&1] fully written
        __builtin_amdgcn_s_barrier();

        const short* Bl = Bt[tile & 1];
        const short* Ee = Esh + tile * 128;
        const short* Gg = Gsh + tile * 128;
        #pragma unroll
        for (int s = 0; s < 4; ++s) {
            const uint4 Eu = *(const uint4*)&Ee[s * 32 + k0];   // 8 f16 (broadcast per quad)
            const uint4 Gu = *(const uint4*)&Gg[s * 32 + k0];
            f16x2 Ep[4] = {bcH(Eu.x), bcH(Eu.y), bcH(Eu.z), bcH(Eu.w)};
            f16x2 Gp[4] = {bcH(Gu.x), bcH(Gu.y), bcH(Gu.z), bcH(Gu.w)};
            const short* bb = Bl + (size_t)((s * 4 + quad) * 64 + li) * 8;
            f16x8 b0 = __builtin_bit_cast(f16x8, *(const bf16x8*)(bb));
            f16x8 b1 = __builtin_bit_cast(f16x8, *(const bf16x8*)(bb + 128));
            f16x8 b2 = __builtin_bit_cast(f16x8, *(const bf16x8*)(bb + 256));
            f16x8 b3 = __builtin_bit_cast(f16x8, *(const bf16x8*)(bb + 384));
            #pragma unroll
            for (int f = 0; f < 4; ++f) {
                const unsigned int wsel = (s == 0) ? bw[f].x : (s == 1) ? bw[f].y
                                        : (s == 2) ? bw[f].z : bw[f].w;
                const unsigned int byt = (wsel >> k0) & 0xFFu;
                u32x4 au;
                #pragma unroll
                for (int d2 = 0; d2 < 4; ++d2) {
                    // mask word: lo16 = sext(bit 2d), hi16 = sext(bit 2d+1)
                    const unsigned mw = (unsigned)__builtin_amdgcn_perm(
                        (unsigned)sext_bit(byt, 2 * d2 + 1),
                        (unsigned)sext_bit(byt, 2 * d2), 0x05040100u);
                    const f16x2 tv = Gp[d2] * Rp[f];                       // v_pk_mul_f16
                    const f16x2 pv = __builtin_elementwise_max(Ep[d2], tv); // v_pk_max_f16
                    au[d2] = __builtin_bit_cast(unsigned, pv) & mw;
                }
                const f16x8 a = __builtin_bit_cast(f16x8, au);
                __builtin_amdgcn_s_setprio(1);
                acc[f][0] = __builtin_amdgcn_mfma_f32_16x16x32_f16(a, b0, acc[f][0], 0, 0, 0);
                acc[f][1] = __builtin_amdgcn_mfma_f32_16x16x32_f16(a, b1, acc[f][1], 0, 0, 0);
                acc[f][2] = __builtin_amdgcn_mfma_f32_16x16x32_f16(a, b2, acc[f][2], 0, 0, 0);
                acc[f][3] = __builtin_amdgcn_mfma_f32_16x16x32_f16(a, b3, acc[f][3], 0, 0, 0);
                c5[f]     = __builtin_amdgcn_mfma_f32_16x16x32_f16(a, ones, c5[f], 0, 0, 0);
                __builtin_amdgcn_s_setprio(0);
            }
        }
    }

    const size_t so = (size_t)(slab * gridDim.y + h);
    #pragma unroll
    for (int f = 0; f < 4; ++f) {
        #pragma unroll
        for (int t4 = 0; t4 < 4; ++t4)
            #pragma unroll
            for (int r = 0; r < 4; ++r) {
                const int row = i0 + w * 64 + f * 16 + quad * 4 + r;
                num[(so * N_NODES + row) * D + t4 * 16 + li] = f2h(acc[f][t4][r]);
            }
        if (li == 0)
            #pragma unroll
            for (int r = 0; r < 4; ++r)
                den[so * N_NODES + i0 + w * 64 + f * 16 + quad * 4 + r] = c5[f][r];
    }
}

// ---------------------------------------------------------------- layer-1 combine (JS=S1): norm+fallback+ELU, f16 out
__global__ void k_post1(const short* __restrict__ num, const float* __restrict__ den,
                        const float* __restrict__ colmean, short* __restrict__ hcat) {
    const int h   = blockIdx.y;
    const int i0  = blockIdx.x * 64;
    const int t   = threadIdx.x;
    const int row = i0 + (t >> 2);
    const int cb  = (t & 3) * 16;
    const size_t HN = (size_t)gridDim.y * N_NODES;
    const size_t r0 = (size_t)h * N_NODES + row;
    float dsum = 0.f;
    #pragma unroll
    for (int s = 0; s < S1; ++s) dsum += den[s * HN + r0];
    const bool  uni  = !(dsum > 0.f);
    const float linv = uni ? 0.f : 1.f / dsum;
    #pragma unroll
    for (int c = 0; c < 4; ++c) {
        const int col = cb + c * 4;
        float4 v = {0.f, 0.f, 0.f, 0.f};
        #pragma unroll
        for (int s = 0; s < S1; ++s) {
            ushort4 a = *(const ushort4*)&num[(s * HN + r0) * D + col];
            v.x += h2f(a.x); v.y += h2f(a.y); v.z += h2f(a.z); v.w += h2f(a.w);
        }
        v.x *= linv; v.y *= linv; v.z *= linv; v.w *= linv;
        if (uni) v = *(const float4*)&colmean[h * D + col];
        v.x = v.x > 0.f ? v.x : __expf(v.x) - 1.f;
        v.y = v.y > 0.f ? v.y : __expf(v.y) - 1.f;
        v.z = v.z > 0.f ? v.z : __expf(v.z) - 1.f;
        v.w = v.w > 0.f ? v.w : __expf(v.w) - 1.f;
        ushort4 o;
        o.x = (unsigned short)f2h(v.x); o.y = (unsigned short)f2h(v.y);
        o.z = (unsigned short)f2h(v.z); o.w = (unsigned short)f2h(v.w);
        *(ushort4*)&hcat[(size_t)row * (H * D) + h * D + col] = o;
    }
}

// ---------------------------------------------------------------- layer-2 combine (JS=S2) + ELU + log_softmax
__global__ void k_lsm(const short* __restrict__ num, const float* __restrict__ den,
                      const float* __restrict__ cm, float* __restrict__ out) {
    const int n    = blockIdx.x * 4 + (threadIdx.x >> 6);
    const int lane = threadIdx.x & 63;
    float v = 0.f, ds = 0.f;
    #pragma unroll
    for (int s = 0; s < S2; ++s)
        v += h2f((unsigned short)num[((size_t)s * N_NODES + n) * D + lane]);
    #pragma unroll
    for (int s = 0; s < S2; ++s) ds += den[(size_t)s * N_NODES + n];
    v = (ds > 0.f) ? v / ds : cm[lane];
    v = v > 0.f ? v : __expf(v) - 1.f;
    float mx = v;
    #pragma unroll
    for (int off = 32; off > 0; off >>= 1) mx = fmaxf(mx, __shfl_xor(mx, off));
    float ex = __expf(v - mx);
    float sum = ex;
    #pragma unroll
    for (int off = 32; off > 0; off >>= 1) sum += __shfl_xor(sum, off);
    out[(size_t)n * D + lane] = (v - mx) - __logf(sum);
}

// ----------------------------------------------------------------
extern "C" void kernel_launch(void* const* d_in, const int* in_sizes, int n_in,
                              void* d_out, int out_size, void* d_ws, size_t ws_size,
                              hipStream_t stream) {
    const float* x      = (const float*)d_in[0];
    const int*   adj    = (const int*)d_in[1];
    const float* W      = (const float*)d_in[2];
    const float* a_src  = (const float*)d_in[3];
    const float* a_dst  = (const float*)d_in[4];
    const float* W_o    = (const float*)d_in[5];
    const float* ao_src = (const float*)d_in[6];
    const float* ao_dst = (const float*)d_in[7];
    float* out = (float*)d_out;

    char* wsp = (char*)d_ws;
    size_t off = 0;
    auto alloc = [&](size_t bytes) -> void* {
        void* p = wsp + off;
        off += (bytes + 255) & ~(size_t)255;
        return p;
    };
    unsigned* adj_bits = (unsigned*)alloc((size_t)N_NODES * NWORDS * 8);
    short*    Xbf   = (short*)alloc((size_t)N_NODES * FDIM * 2);
    short*    WF1   = (short*)alloc((size_t)H * 64 * D * 8 * 2);
    short*    WoF   = (short*)alloc((size_t)64 * D * 8 * 2);
    short*    WhB   = (short*)alloc((size_t)H * N_NODES * D * 2);
    float*    fs1   = (float*)alloc((size_t)H * N_NODES * 4);
    float*    fd1   = (float*)alloc((size_t)H * N_NODES * 4);
    unsigned* gme1  = (unsigned*)alloc((size_t)H * 4);
    float*    cm1   = (float*)alloc((size_t)H * D * 4);
    short*    num1  = (short*)alloc((size_t)S1 * H * N_NODES * D * 2);
    float*    den1  = (float*)alloc((size_t)S1 * H * N_NODES * 4);
    short*    hcat  = (short*)alloc((size_t)N_NODES * H * D * 2);
    short*    WhoB  = (short*)alloc((size_t)N_NODES * D * 2);
    float*    fs2   = (float*)alloc((size_t)N_NODES * 4);
    float*    fd2   = (float*)alloc((size_t)N_NODES * 4);
    unsigned* gme2  = (unsigned*)alloc(4);
    float*    cm2   = (float*)alloc((size_t)D * 4);
    short*    num2  = (short*)alloc((size_t)S2 * N_NODES * D * 2);
    float*    den2  = (float*)alloc((size_t)S2 * N_NODES * 4);

    k_pre  <<<dim3(1 + NB_BITS + NB_X + NB_W + NB_WO), dim3(256), 0, stream>>>(
        adj, x, W, W_o, adj_bits, Xbf, WF1, WoF, cm1, cm2, gme1, gme2);

    // layer 1 (8 heads, concat + ELU)
    k_gemm <<<dim3(N_NODES / 64, H), dim3(256), 0, stream>>>(Xbf, WF1, a_src, a_dst,
                                                             WhB, fs1, fd1, gme1, cm1);
    k_accum<<<dim3(N_NODES / 128, H, S1), dim3(128), 0, stream>>>(adj_bits, WhB, fs1, fd1, gme1,
                                                                  num1, den1, N_NODES / S1);
    k_post1<<<dim3(N_NODES / 64, H), dim3(256), 0, stream>>>(num1, den1, cm1, hcat);

    // layer 2 (single output head)
    k_gemm <<<dim3(N_NODES / 64, 1), dim3(256), 0, stream>>>(hcat, WoF, ao_src, ao_dst,
                                                             WhoB, fs2, fd2, gme2, cm2);
    k_accum<<<dim3(N_NODES / 128, 1, S2), dim3(128), 0, stream>>>(adj_bits, WhoB, fs2, fd2, gme2,
                                                                  num2, den2, N_NODES / S2);
    k_lsm  <<<dim3(N_NODES / 4), dim3(256), 0, stream>>>(num2, den2, cm2, out);
}